// Round 3
// baseline (267.149 us; speedup 1.0000x reference)
//
#include <hip/hip_runtime.h>

typedef __attribute__((ext_vector_type(8))) _Float16 half8;
typedef __attribute__((ext_vector_type(4))) _Float16 half4;
typedef __attribute__((ext_vector_type(4))) float f32x4;

#define MFMA_K32(a, b, c) __builtin_amdgcn_mfma_f32_16x16x32_f16((a), (b), (c), 0, 0, 0)
#define MFMA_K16(a, b, c) __builtin_amdgcn_mfma_f32_16x16x16f16((a), (b), (c), 0, 0, 0)

// async global->LDS, 16B per lane; LDS dest = wave-uniform base + lane*16
__device__ inline void async16(const _Float16* g, _Float16* l) {
    __builtin_amdgcn_global_load_lds(
        (const __attribute__((address_space(1))) void*)g,
        (__attribute__((address_space(3))) void*)l, 16, 0, 0);
}

// ---------------------------------------------------------------------------
// B=32, S=512, Dm=768, H=12, d=64, M=16384.
// probs = (s*0.125+5)^2; probs /= (rowsum+1e-10); probs *= mask; ctx = probs@V
// Folded: ctx = (sum_k w_k * (mask_k v_k)) / (sum_k w_k + 1e-10)
// ---------------------------------------------------------------------------

// Kernel 0: X f32 -> f16
__global__ __launch_bounds__(256) void xcast(const float* __restrict__ X,
                                             _Float16* __restrict__ Xh)
{
    size_t idx = ((size_t)blockIdx.x * 256 + threadIdx.x) * 8;
    float4 a = *(const float4*)(X + idx);
    float4 c = *(const float4*)(X + idx + 4);
    half8 hv;
    hv[0] = (_Float16)a.x; hv[1] = (_Float16)a.y;
    hv[2] = (_Float16)a.z; hv[3] = (_Float16)a.w;
    hv[4] = (_Float16)c.x; hv[5] = (_Float16)c.y;
    hv[6] = (_Float16)c.z; hv[7] = (_Float16)c.w;
    *(half8*)(Xh + idx) = hv;
}

// Kernel 1: weights transpose+cast: Wt[n][k] = (f16) W[k][n]
__global__ __launch_bounds__(256) void wcast_kernel(
    const float* __restrict__ W0, const float* __restrict__ W1,
    const float* __restrict__ W2,
    _Float16* __restrict__ T0, _Float16* __restrict__ T1,
    _Float16* __restrict__ T2)
{
    int z = blockIdx.z;
    const float* W = (z == 0) ? W0 : (z == 1) ? W1 : W2;
    _Float16* T = (z == 0) ? T0 : (z == 1) ? T1 : T2;
    __shared__ float tile[32][33];
    int n0 = blockIdx.x * 32, k0 = blockIdx.y * 32;
    int tx = threadIdx.x & 31, ty = threadIdx.x >> 5;
#pragma unroll
    for (int r = 0; r < 4; ++r)
        tile[ty + 8 * r][tx] = W[(size_t)(k0 + ty + 8 * r) * 768 + n0 + tx];
    __syncthreads();
#pragma unroll
    for (int r = 0; r < 4; ++r)
        T[(size_t)(n0 + ty + 8 * r) * 768 + k0 + tx] =
            (_Float16)tile[tx][ty + 8 * r];
}

// ---------------------------------------------------------------------------
// Kernel 2: fused QKV GEMM, C[16384 x 2304] over z = n/768.
// m97 structure: global_load_lds w=16 staging, 128x128 tile, BK=32,
// XOR-swizzled 16B blocks in LDS (slot j holds global block j^((row>>1)&3))
// -> staging DMA stays lane-contiguous AND ds_read_b128 is 2-way (free).
// Q,K out: [B,H,S,64] f16. V out: [B,H,64,S] f16, pre-multiplied by mask.
// ---------------------------------------------------------------------------
__global__ __launch_bounds__(256) void qkv_gemm(
    const _Float16* __restrict__ Xh,
    const _Float16* __restrict__ W0, const _Float16* __restrict__ W1,
    const _Float16* __restrict__ W2,
    const float* __restrict__ b0, const float* __restrict__ b1,
    const float* __restrict__ b2,
    const float* __restrict__ mask,
    _Float16* __restrict__ Qo, _Float16* __restrict__ Ko,
    _Float16* __restrict__ Vo)
{
    int z = blockIdx.y / 6;
    int n0 = (blockIdx.y % 6) * 128;
    int m0 = blockIdx.x * 128;
    const _Float16* Wt = (z == 0) ? W0 : (z == 1) ? W1 : W2;
    const float* bias = (z == 0) ? b0 : (z == 1) ? b1 : b2;

    __shared__ __attribute__((aligned(16))) _Float16 As[128 * 32];
    __shared__ __attribute__((aligned(16))) _Float16 Bs[128 * 32];

    int t = threadIdx.x;
    int wave = t >> 6, lane = t & 63, quad = lane >> 4, l16 = lane & 15;
    int wm = (wave & 1) * 64, wn = (wave >> 1) * 64;

    // staging geometry: lane covers row = t>>2 (and +64), 16B block (t&3),
    // loading the swizzled global block so flat LDS slot order matches DMA.
    int srow0 = t >> 2;
    int sblk = (t & 3) ^ ((srow0 >> 1) & 3);  // same for row+64 (64>>1 % 4 == 0)

    const _Float16* ga0 = Xh + (size_t)(m0 + srow0) * 768 + sblk * 8;
    const _Float16* ga1 = Xh + (size_t)(m0 + 64 + srow0) * 768 + sblk * 8;
    const _Float16* gb0 = Wt + (size_t)(n0 + srow0) * 768 + sblk * 8;
    const _Float16* gb1 = Wt + (size_t)(n0 + 64 + srow0) * 768 + sblk * 8;
    _Float16* la0 = As + wave * 512;
    _Float16* la1 = As + 2048 + wave * 512;
    _Float16* lb0 = Bs + wave * 512;
    _Float16* lb1 = Bs + 2048 + wave * 512;

    int swz = ((quad ^ ((l16 >> 1) & 3)) << 3);  // read-side deswizzle (halves)

    f32x4 acc[4][4] = {};

    for (int k0 = 0; k0 < 768; k0 += 32) {
        async16(ga0, la0); async16(ga1, la1);
        async16(gb0, lb0); async16(gb1, lb1);
        ga0 += 32; ga1 += 32; gb0 += 32; gb1 += 32;
        __syncthreads();  // drains vmcnt -> tiles staged; prev reads done before issue
        half8 af[4], bf[4];
#pragma unroll
        for (int i = 0; i < 4; ++i)
            af[i] = *(const half8*)&As[(wm + i * 16 + l16) * 32 + swz];
#pragma unroll
        for (int j = 0; j < 4; ++j)
            bf[j] = *(const half8*)&Bs[(wn + j * 16 + l16) * 32 + swz];
#pragma unroll
        for (int i = 0; i < 4; ++i)
#pragma unroll
            for (int j = 0; j < 4; ++j)
                acc[i][j] = MFMA_K32(af[i], bf[j], acc[i][j]);
        __syncthreads();
    }

    // epilogue: C row = wm+i*16+quad*4+r ; col = wn+j*16+l16
    float mk[4][4];
    if (z == 2) {
#pragma unroll
        for (int i = 0; i < 4; ++i) {
            int mbase = m0 + wm + i * 16 + quad * 4;
            int bb = mbase >> 9, s = mbase & 511;
#pragma unroll
            for (int r = 0; r < 4; ++r)
                mk[i][r] = mask[(size_t)bb * 512 + s + r];
        }
    }
#pragma unroll
    for (int j = 0; j < 4; ++j) {
        int n = n0 + wn + j * 16 + l16;
        float bv = bias[n];
        int hh = n >> 6, d = n & 63;
#pragma unroll
        for (int i = 0; i < 4; ++i) {
            int mbase = m0 + wm + i * 16 + quad * 4;
            int bb = mbase >> 9, s = mbase & 511;
            if (z < 2) {
                _Float16* outp = (z == 0) ? Qo : Ko;
#pragma unroll
                for (int r = 0; r < 4; ++r) {
                    size_t off = (((size_t)(bb * 12 + hh)) * 512 + s + r) * 64 + d;
                    outp[off] = (_Float16)(acc[i][j][r] + bv);
                }
            } else {
                // V^T [B,H,64,S], premasked; regs = consecutive tokens -> 8B store
                half4 pk;
#pragma unroll
                for (int r = 0; r < 4; ++r)
                    pk[r] = (_Float16)((acc[i][j][r] + bv) * mk[i][r]);
                size_t off = (((size_t)(bb * 12 + hh)) * 64 + d) * 512 + s;
                *(half4*)&Vo[off] = pk;
            }
        }
    }
}

// ---------------------------------------------------------------------------
// Kernel 3: power-law attention, P-in-registers.
// Block = 2 waves x 64 queries (128 q), grid (4, H, B).
// Per 64-key tile: S^T = K Q^T via 16x16x32 MFMA (C: row=key, col=query).
//   Lane then holds P[q=l16][k=quad*4+r] == A-fragment of 16x16x16 f16 MFMA.
//   rowsum via MFMA with constant ones B-frag (C row=q, same value all cols).
//   ctx += P @ V via 16x16x16 MFMA, B-frag half4 reads from V^T LDS tile.
// V is premasked; rowsum over unmasked w == reference semantics.
// Staging: 128 threads x 32 halves (4x half8) per tile -> FULL 64x64 tile
// coverage (round-2 bug: only 16 halves/thread -> half the tile was
// uninitialized LDS -> NaN).
// ---------------------------------------------------------------------------
__global__ __launch_bounds__(128) void attn_kernel(
    const _Float16* __restrict__ Q, const _Float16* __restrict__ K,
    const _Float16* __restrict__ Vt, float* __restrict__ out)
{
    __shared__ __attribute__((aligned(16))) _Float16 Ks[64 * 88];  // [key][d]
    __shared__ __attribute__((aligned(16))) _Float16 Vs[64 * 88];  // [d][key]

    int t = threadIdx.x;
    int wave = t >> 6, lane = t & 63, quad = lane >> 4, l16 = lane & 15;
    int h = blockIdx.y, b = blockIdx.z;
    size_t bh = (size_t)b * 12 + h;
    const _Float16* Qp = Q + bh * (512 * 64);
    const _Float16* Kp = K + bh * (512 * 64);
    const _Float16* Vp = Vt + bh * (64 * 512);
    int qbase = blockIdx.x * 128 + wave * 64;

    // Q fragments (B-operand layout == row-major half8 at [query][d])
    half8 qf[4][2];
#pragma unroll
    for (int i = 0; i < 4; ++i)
#pragma unroll
        for (int ks = 0; ks < 2; ++ks)
            qf[i][ks] = *(const half8*)(Qp + (size_t)(qbase + i * 16 + l16) * 64 +
                                        ks * 32 + quad * 8);

    f32x4 ctx[4][4] = {};
    f32x4 rsum[4] = {};
    const half4 ones = {(_Float16)1.f, (_Float16)1.f, (_Float16)1.f, (_Float16)1.f};

    int srow = t >> 1, spart = (t & 1) * 32;  // 2 threads/row, 32 halves each

    for (int kt = 0; kt < 8; ++kt) {
        int k0 = kt * 64;
        const _Float16* kg = Kp + (size_t)(k0 + srow) * 64 + spart;
        half8 ka0 = *(const half8*)kg;
        half8 ka1 = *(const half8*)(kg + 8);
        half8 ka2 = *(const half8*)(kg + 16);
        half8 ka3 = *(const half8*)(kg + 24);
        const _Float16* vg = Vp + (size_t)srow * 512 + k0 + spart;
        half8 va0 = *(const half8*)vg;
        half8 va1 = *(const half8*)(vg + 8);
        half8 va2 = *(const half8*)(vg + 16);
        half8 va3 = *(const half8*)(vg + 24);
        __syncthreads();  // all waves done reading previous tile
        *(half8*)&Ks[srow * 88 + spart] = ka0;
        *(half8*)&Ks[srow * 88 + spart + 8] = ka1;
        *(half8*)&Ks[srow * 88 + spart + 16] = ka2;
        *(half8*)&Ks[srow * 88 + spart + 24] = ka3;
        *(half8*)&Vs[srow * 88 + spart] = va0;
        *(half8*)&Vs[srow * 88 + spart + 8] = va1;
        *(half8*)&Vs[srow * 88 + spart + 16] = va2;
        *(half8*)&Vs[srow * 88 + spart + 24] = va3;
        __syncthreads();

#pragma unroll
        for (int kb = 0; kb < 4; ++kb) {
            half8 kf0 = *(const half8*)&Ks[(kb * 16 + l16) * 88 + quad * 8];
            half8 kf1 = *(const half8*)&Ks[(kb * 16 + l16) * 88 + 32 + quad * 8];
            half4 pA[4];
#pragma unroll
            for (int i = 0; i < 4; ++i) {
                f32x4 sc = {0.f, 0.f, 0.f, 0.f};
                sc = MFMA_K32(kf0, qf[i][0], sc);
                sc = MFMA_K32(kf1, qf[i][1], sc);
                half4 p;
#pragma unroll
                for (int r = 0; r < 4; ++r) {
                    float s = sc[r] * 0.125f + 5.0f;
                    p[r] = (_Float16)(s * s);
                }
                pA[i] = p;
                rsum[i] = MFMA_K16(p, ones, rsum[i]);
            }
#pragma unroll
            for (int n = 0; n < 4; ++n) {
                half4 vf = *(const half4*)&Vs[(n * 16 + l16) * 88 + kb * 16 + quad * 4];
#pragma unroll
                for (int i = 0; i < 4; ++i)
                    ctx[i][n] = MFMA_K16(pA[i], vf, ctx[i][n]);
            }
        }
    }

    // epilogue: rsum reg r and ctx reg r both live on C row = quad*4+r
#pragma unroll
    for (int i = 0; i < 4; ++i) {
        f32x4 inv;
#pragma unroll
        for (int r = 0; r < 4; ++r)
            inv[r] = 1.0f / (rsum[i][r] + 1e-10f);
#pragma unroll
        for (int n = 0; n < 4; ++n)
#pragma unroll
            for (int r = 0; r < 4; ++r) {
                int q = qbase + i * 16 + quad * 4 + r;
                int d = n * 16 + l16;
                out[((size_t)b * 512 + q) * 768 + h * 64 + d] =
                    ctx[i][n][r] * inv[r];
            }
    }
}

// ---------------------------------------------------------------------------
extern "C" void kernel_launch(void* const* d_in, const int* in_sizes, int n_in,
                              void* d_out, int out_size, void* d_ws, size_t ws_size,
                              hipStream_t stream)
{
    const float* hs   = (const float*)d_in[0];
    const float* mask = (const float*)d_in[1];
    const float* Wq   = (const float*)d_in[2];
    const float* bq   = (const float*)d_in[3];
    const float* Wk   = (const float*)d_in[4];
    const float* bk   = (const float*)d_in[5];
    const float* Wv   = (const float*)d_in[6];
    const float* bv   = (const float*)d_in[7];
    float* out = (float*)d_out;

    char* ws = (char*)d_ws;
    _Float16* Wtq = (_Float16*)ws;            // 3 x 768*768 halves
    _Float16* Wtk = Wtq + 768 * 768;
    _Float16* Wtv = Wtk + 768 * 768;
    _Float16* Qb  = Wtv + 768 * 768;          // 3 x 16384*768 halves
    _Float16* Kb  = Qb + 16384 * 768;
    _Float16* Vb  = Kb + 16384 * 768;
    // ws use ~79 MB.
    // Xh scratch lives in d_out (50 MB f32; Xh needs 25 MB and is dead before
    // attn writes out).
    _Float16* Xh = (_Float16*)d_out;

    xcast<<<dim3(6144), 256, 0, stream>>>(hs, Xh);
    wcast_kernel<<<dim3(24, 24, 3), 256, 0, stream>>>(Wq, Wk, Wv, Wtq, Wtk, Wtv);
    qkv_gemm<<<dim3(128, 18), 256, 0, stream>>>(Xh, Wtq, Wtk, Wtv,
                                                bq, bk, bv, mask, Qb, Kb, Vb);
    attn_kernel<<<dim3(4, 12, 32), 128, 0, stream>>>(Qb, Kb, Vb, out);
}

// Round 4
// 241.285 us; speedup vs baseline: 1.1072x; 1.1072x over previous
//
#include <hip/hip_runtime.h>

typedef __attribute__((ext_vector_type(8))) _Float16 half8;
typedef __attribute__((ext_vector_type(4))) _Float16 half4;
typedef __attribute__((ext_vector_type(4))) float f32x4;

#define MFMA_K32(a, b, c) __builtin_amdgcn_mfma_f32_16x16x32_f16((a), (b), (c), 0, 0, 0)
#define MFMA_K16(a, b, c) __builtin_amdgcn_mfma_f32_16x16x16f16((a), (b), (c), 0, 0, 0)

// async global->LDS, 16B per lane; LDS dest = wave-uniform base + lane*16
__device__ inline void async16(const _Float16* g, _Float16* l) {
    __builtin_amdgcn_global_load_lds(
        (const __attribute__((address_space(1))) void*)g,
        (__attribute__((address_space(3))) void*)l, 16, 0, 0);
}

// ---------------------------------------------------------------------------
// B=32, S=512, Dm=768, H=12, d=64, M=16384.
// probs = (s*0.125+5)^2; probs /= (rowsum+1e-10); probs *= mask; ctx = probs@V
// Folded: ctx = (sum_k w_k * (mask_k v_k)) / (sum_k w_k + 1e-10)
// Q is pre-scaled by 0.125 at the GEMM epilogue, so attn uses s = q.k + 5.
// ---------------------------------------------------------------------------

// Kernel 0: X f32 -> f16
__global__ __launch_bounds__(256) void xcast(const float* __restrict__ X,
                                             _Float16* __restrict__ Xh)
{
    size_t idx = ((size_t)blockIdx.x * 256 + threadIdx.x) * 8;
    float4 a = *(const float4*)(X + idx);
    float4 c = *(const float4*)(X + idx + 4);
    half8 hv;
    hv[0] = (_Float16)a.x; hv[1] = (_Float16)a.y;
    hv[2] = (_Float16)a.z; hv[3] = (_Float16)a.w;
    hv[4] = (_Float16)c.x; hv[5] = (_Float16)c.y;
    hv[6] = (_Float16)c.z; hv[7] = (_Float16)c.w;
    *(half8*)(Xh + idx) = hv;
}

// Kernel 1: weights transpose+cast: Wt[n][k] = (f16) W[k][n]
__global__ __launch_bounds__(256) void wcast_kernel(
    const float* __restrict__ W0, const float* __restrict__ W1,
    const float* __restrict__ W2,
    _Float16* __restrict__ T0, _Float16* __restrict__ T1,
    _Float16* __restrict__ T2)
{
    int z = blockIdx.z;
    const float* W = (z == 0) ? W0 : (z == 1) ? W1 : W2;
    _Float16* T = (z == 0) ? T0 : (z == 1) ? T1 : T2;
    __shared__ float tile[32][33];
    int n0 = blockIdx.x * 32, k0 = blockIdx.y * 32;
    int tx = threadIdx.x & 31, ty = threadIdx.x >> 5;
#pragma unroll
    for (int r = 0; r < 4; ++r)
        tile[ty + 8 * r][tx] = W[(size_t)(k0 + ty + 8 * r) * 768 + n0 + tx];
    __syncthreads();
#pragma unroll
    for (int r = 0; r < 4; ++r)
        T[(size_t)(n0 + ty + 8 * r) * 768 + k0 + tx] =
            (_Float16)tile[tx][ty + 8 * r];
}

// ---------------------------------------------------------------------------
// Kernel 2: fused QKV GEMM, C[16384 x 2304] over z = n/768.
// BK=64 (12 K-iters, half the barrier/vmcnt drains of BK=32).
// XOR swizzle on 16B chunks: LDS chunk j of a row holds global chunk
// j ^ (row&7); readers use slot = g ^ (row&7). Frag reads land 2-way (free).
// Q out pre-scaled 0.125. V out transposed [B,H,64,S], premasked.
// ---------------------------------------------------------------------------
__global__ __launch_bounds__(256) void qkv_gemm(
    const _Float16* __restrict__ Xh,
    const _Float16* __restrict__ W0, const _Float16* __restrict__ W1,
    const _Float16* __restrict__ W2,
    const float* __restrict__ b0, const float* __restrict__ b1,
    const float* __restrict__ b2,
    const float* __restrict__ mask,
    _Float16* __restrict__ Qo, _Float16* __restrict__ Ko,
    _Float16* __restrict__ Vo)
{
    int z = blockIdx.y / 6;
    int n0 = (blockIdx.y % 6) * 128;
    int m0 = blockIdx.x * 128;
    const _Float16* Wt = (z == 0) ? W0 : (z == 1) ? W1 : W2;
    const float* bias = (z == 0) ? b0 : (z == 1) ? b1 : b2;

    __shared__ __attribute__((aligned(16))) _Float16 As[128 * 64];  // 16 KB
    __shared__ __attribute__((aligned(16))) _Float16 Bs[128 * 64];  // 16 KB

    int t = threadIdx.x;
    int wave = t >> 6, lane = t & 63, quad = lane >> 4, l16 = lane & 15;
    int wm = (wave & 1) * 64, wn = (wave >> 1) * 64;

    // staging: chunk index c = slot*256 + t; row = c>>3, LDS slot j = c&7,
    // global chunk g = j ^ (row&7).  (slot*256 doesn't change row&7 or j.)
    int srow = t >> 3;               // 0..31 (row advances +32 per slot)
    int sg = (t & 7) ^ (srow & 7);   // global chunk this thread fetches

    const _Float16* gA = Xh + (size_t)(m0 + srow) * 768 + sg * 8;
    const _Float16* gB = Wt + (size_t)(n0 + srow) * 768 + sg * 8;
    _Float16* lA = As + t * 8;
    _Float16* lB = Bs + t * 8;

    f32x4 acc[4][4] = {};

    for (int k0 = 0; k0 < 768; k0 += 64) {
#pragma unroll
        for (int q = 0; q < 4; ++q) {
            async16(gA + (size_t)q * 32 * 768 + k0, lA + q * 2048);
            async16(gB + (size_t)q * 32 * 768 + k0, lB + q * 2048);
        }
        __syncthreads();  // drains vmcnt -> tiles staged
#pragma unroll
        for (int ks = 0; ks < 2; ++ks) {
            half8 af[4], bf[4];
#pragma unroll
            for (int i = 0; i < 4; ++i) {
                int row = wm + i * 16 + l16;
                af[i] = *(const half8*)&As[row * 64 +
                                           (((ks << 2) + quad) ^ (row & 7)) * 8];
            }
#pragma unroll
            for (int j = 0; j < 4; ++j) {
                int row = wn + j * 16 + l16;
                bf[j] = *(const half8*)&Bs[row * 64 +
                                           (((ks << 2) + quad) ^ (row & 7)) * 8];
            }
#pragma unroll
            for (int i = 0; i < 4; ++i)
#pragma unroll
                for (int j = 0; j < 4; ++j)
                    acc[i][j] = MFMA_K32(af[i], bf[j], acc[i][j]);
        }
        __syncthreads();
    }

    // epilogue: C row = wm+i*16+quad*4+r ; col = wn+j*16+l16
    float mk[4][4];
    if (z == 2) {
#pragma unroll
        for (int i = 0; i < 4; ++i) {
            int mbase = m0 + wm + i * 16 + quad * 4;
            int bb = mbase >> 9, s = mbase & 511;
#pragma unroll
            for (int r = 0; r < 4; ++r)
                mk[i][r] = mask[(size_t)bb * 512 + s + r];
        }
    }
#pragma unroll
    for (int j = 0; j < 4; ++j) {
        int n = n0 + wn + j * 16 + l16;
        float bv = bias[n];
        int hh = n >> 6, d = n & 63;
#pragma unroll
        for (int i = 0; i < 4; ++i) {
            int mbase = m0 + wm + i * 16 + quad * 4;
            int bb = mbase >> 9, s = mbase & 511;
            if (z == 0) {
                // Q, pre-scaled by 0.125 (score scale folded in)
#pragma unroll
                for (int r = 0; r < 4; ++r) {
                    size_t off = (((size_t)(bb * 12 + hh)) * 512 + s + r) * 64 + d;
                    Qo[off] = (_Float16)((acc[i][j][r] + bv) * 0.125f);
                }
            } else if (z == 1) {
#pragma unroll
                for (int r = 0; r < 4; ++r) {
                    size_t off = (((size_t)(bb * 12 + hh)) * 512 + s + r) * 64 + d;
                    Ko[off] = (_Float16)(acc[i][j][r] + bv);
                }
            } else {
                // V^T [B,H,64,S], premasked; regs = consecutive tokens -> 8B store
                half4 pk;
#pragma unroll
                for (int r = 0; r < 4; ++r)
                    pk[r] = (_Float16)((acc[i][j][r] + bv) * mk[i][r]);
                size_t off = (((size_t)(bb * 12 + hh)) * 64 + d) * 512 + s;
                *(half4*)&Vo[off] = pk;
            }
        }
    }
}

// ---------------------------------------------------------------------------
// Kernel 3: power-law attention, P-in-registers.
// Block = 4 waves x 64 queries (256 q), grid (2, H, B) = 768 blocks
// (3 blocks/CU fully resident, 12 waves/CU for latency hiding).
// Per 64-key tile: S^T = K Q^T via 16x16x32 MFMA (C: row=key, col=query).
//   Lane holds P[q=l16][k=quad*4+r] == A-fragment of 16x16x16 f16 MFMA.
//   rowsum via MFMA with ones B-frag; ctx += P @ V via 16x16x16 MFMA.
// V premasked; rowsum over unmasked w == reference semantics.
// Staging: 256 threads x 16 halves per array -> full 64x64 tiles.
// ---------------------------------------------------------------------------
__global__ __launch_bounds__(256) void attn_kernel(
    const _Float16* __restrict__ Q, const _Float16* __restrict__ K,
    const _Float16* __restrict__ Vt, float* __restrict__ out)
{
    __shared__ __attribute__((aligned(16))) _Float16 Ks[64 * 88];  // [key][d]
    __shared__ __attribute__((aligned(16))) _Float16 Vs[64 * 88];  // [d][key]

    int t = threadIdx.x;
    int wave = t >> 6, lane = t & 63, quad = lane >> 4, l16 = lane & 15;
    int h = blockIdx.y, b = blockIdx.z;
    size_t bh = (size_t)b * 12 + h;
    const _Float16* Qp = Q + bh * (512 * 64);
    const _Float16* Kp = K + bh * (512 * 64);
    const _Float16* Vp = Vt + bh * (64 * 512);
    int qbase = blockIdx.x * 256 + wave * 64;

    // Q fragments (B-operand layout == row-major half8 at [query][d])
    half8 qf[4][2];
#pragma unroll
    for (int i = 0; i < 4; ++i)
#pragma unroll
        for (int ks = 0; ks < 2; ++ks)
            qf[i][ks] = *(const half8*)(Qp + (size_t)(qbase + i * 16 + l16) * 64 +
                                        ks * 32 + quad * 8);

    f32x4 ctx[4][4] = {};
    f32x4 rsum[4] = {};
    const half4 ones = {(_Float16)1.f, (_Float16)1.f, (_Float16)1.f, (_Float16)1.f};

    int srow = t >> 2, spart = (t & 3) * 16;  // 4 threads/row, 16 halves each

    for (int kt = 0; kt < 8; ++kt) {
        int k0 = kt * 64;
        const _Float16* kg = Kp + (size_t)(k0 + srow) * 64 + spart;
        half8 ka0 = *(const half8*)kg;
        half8 ka1 = *(const half8*)(kg + 8);
        const _Float16* vg = Vp + (size_t)srow * 512 + k0 + spart;
        half8 va0 = *(const half8*)vg;
        half8 va1 = *(const half8*)(vg + 8);
        __syncthreads();  // all waves done reading previous tile
        *(half8*)&Ks[srow * 88 + spart] = ka0;
        *(half8*)&Ks[srow * 88 + spart + 8] = ka1;
        *(half8*)&Vs[srow * 88 + spart] = va0;
        *(half8*)&Vs[srow * 88 + spart + 8] = va1;
        __syncthreads();

#pragma unroll
        for (int kb = 0; kb < 4; ++kb) {
            half8 kf0 = *(const half8*)&Ks[(kb * 16 + l16) * 88 + quad * 8];
            half8 kf1 = *(const half8*)&Ks[(kb * 16 + l16) * 88 + 32 + quad * 8];
            half4 pA[4];
#pragma unroll
            for (int i = 0; i < 4; ++i) {
                f32x4 sc = {0.f, 0.f, 0.f, 0.f};
                sc = MFMA_K32(kf0, qf[i][0], sc);
                sc = MFMA_K32(kf1, qf[i][1], sc);
                half4 p;
#pragma unroll
                for (int r = 0; r < 4; ++r) {
                    float s = sc[r] + 5.0f;   // Q pre-scaled by 0.125
                    p[r] = (_Float16)(s * s);
                }
                pA[i] = p;
                rsum[i] = MFMA_K16(p, ones, rsum[i]);
            }
#pragma unroll
            for (int n = 0; n < 4; ++n) {
                half4 vf = *(const half4*)&Vs[(n * 16 + l16) * 88 + kb * 16 + quad * 4];
#pragma unroll
                for (int i = 0; i < 4; ++i)
                    ctx[i][n] = MFMA_K16(pA[i], vf, ctx[i][n]);
            }
        }
    }

    // epilogue: rsum reg r and ctx reg r both live on C row = quad*4+r
#pragma unroll
    for (int i = 0; i < 4; ++i) {
        f32x4 inv;
#pragma unroll
        for (int r = 0; r < 4; ++r)
            inv[r] = 1.0f / (rsum[i][r] + 1e-10f);
#pragma unroll
        for (int n = 0; n < 4; ++n)
#pragma unroll
            for (int r = 0; r < 4; ++r) {
                int q = qbase + i * 16 + quad * 4 + r;
                int d = n * 16 + l16;
                out[((size_t)b * 512 + q) * 768 + h * 64 + d] =
                    ctx[i][n][r] * inv[r];
            }
    }
}

// ---------------------------------------------------------------------------
extern "C" void kernel_launch(void* const* d_in, const int* in_sizes, int n_in,
                              void* d_out, int out_size, void* d_ws, size_t ws_size,
                              hipStream_t stream)
{
    const float* hs   = (const float*)d_in[0];
    const float* mask = (const float*)d_in[1];
    const float* Wq   = (const float*)d_in[2];
    const float* bq   = (const float*)d_in[3];
    const float* Wk   = (const float*)d_in[4];
    const float* bk   = (const float*)d_in[5];
    const float* Wv   = (const float*)d_in[6];
    const float* bv   = (const float*)d_in[7];
    float* out = (float*)d_out;

    char* ws = (char*)d_ws;
    _Float16* Wtq = (_Float16*)ws;            // 3 x 768*768 halves
    _Float16* Wtk = Wtq + 768 * 768;
    _Float16* Wtv = Wtk + 768 * 768;
    _Float16* Qb  = Wtv + 768 * 768;          // 3 x 16384*768 halves
    _Float16* Kb  = Qb + 16384 * 768;
    _Float16* Vb  = Kb + 16384 * 768;
    // ws use ~79 MB. Xh scratch lives in d_out (Xh 25 MB, dead before attn).
    _Float16* Xh = (_Float16*)d_out;

    xcast<<<dim3(6144), 256, 0, stream>>>(hs, Xh);
    wcast_kernel<<<dim3(24, 24, 3), 256, 0, stream>>>(Wq, Wk, Wv, Wtq, Wtk, Wtv);
    qkv_gemm<<<dim3(128, 18), 256, 0, stream>>>(Xh, Wtq, Wtk, Wtv,
                                                bq, bk, bv, mask, Qb, Kb, Vb);
    attn_kernel<<<dim3(2, 12, 32), 256, 0, stream>>>(Qb, Kb, Vb, out);
}